// Round 23
// baseline (71.687 us; speedup 1.0000x reference)
//
#include <hip/hip_runtime.h>
#include <hip/hip_bf16.h>

#define EPS_BN 1e-5f

typedef __attribute__((ext_vector_type(8)))  short short8;    // 8 x bf16
typedef __attribute__((ext_vector_type(4)))  float float4v;
typedef __attribute__((ext_vector_type(16))) float float16v;  // 32x32 acc

constexpr int NEWX_ELEMS = 196608;    // B*P*3
constexpr int GRID       = 2048;      // 4 waves/block, GITER groups/wave
constexpr int GITER      = 8;
constexpr int GSTRIDE    = GRID * 4;

constexpr int W0F = 0;      // f32[192]  W0' (64x3)
constexpr int B0F = 192;    // f32[64]
constexpr int B1F = 256;    // f32[64]
constexpr int B2F = 320;    // f32[128]
constexpr int W1B = 1792;   // bytes: ushort[4096]  W1' (64x64) bf16
constexpr int W2B = 10240;  // bytes: ushort[8192]  W2' (128x64) bf16

__device__ __forceinline__ unsigned short f2bf(float x) {
    return __builtin_bit_cast(unsigned short, __float2bfloat16(x));
}
__device__ __forceinline__ unsigned cvtpk(float a, float b) {
    unsigned r;
    asm("v_cvt_pk_bf16_f32 %0, %1, %2" : "=v"(r) : "v"(a), "v"(b));
    return r;
}
// gfx950: vdst.high32 <-> vsrc.low32  (HW-validated R16)
__device__ __forceinline__ void plswap(unsigned &a, unsigned &b) {
    asm("v_permlane32_swap_b32 %0, %1" : "+v"(a), "+v"(b));
}

__global__ void fold_kernel(
    const float* w0, const float* b0, const float* g0,
    const float* be0, const float* m0, const float* v0,
    const float* w1, const float* b1, const float* g1,
    const float* be1, const float* m1, const float* v1,
    const float* w2, const float* b2, const float* g2,
    const float* be2, const float* m2, const float* v2,
    float* __restrict__ ws)
{
    const int tg = blockIdx.x * 256 + threadIdx.x;   // 0..8191
    ushort* w1b = (ushort*)((char*)ws + W1B);
    ushort* w2b = (ushort*)((char*)ws + W2B);
    if (tg < 64) {
        float s0 = g0[tg] * rsqrtf(v0[tg] + EPS_BN);
        ws[B0F + tg] = (b0[tg] - m0[tg]) * s0 + be0[tg];
        ws[W0F + tg*3 + 0] = w0[tg*3 + 0] * s0;
        ws[W0F + tg*3 + 1] = w0[tg*3 + 1] * s0;
        ws[W0F + tg*3 + 2] = w0[tg*3 + 2] * s0;
        float s1 = g1[tg] * rsqrtf(v1[tg] + EPS_BN);
        ws[B1F + tg] = (b1[tg] - m1[tg]) * s1 + be1[tg];
    }
    if (tg < 128) {
        float s2 = g2[tg] * rsqrtf(v2[tg] + EPS_BN);
        ws[B2F + tg] = (b2[tg] - m2[tg]) * s2 + be2[tg];
    }
    if (tg < 4096) {
        int o = tg >> 6;
        float s = g1[o] * rsqrtf(v1[o] + EPS_BN);
        w1b[tg] = f2bf(w1[tg] * s);
    }
    if (tg < 8192) {
        int o = tg >> 6;
        float s = g2[o] * rsqrtf(v2[o] + EPS_BN);
        w2b[tg] = f2bf(w2[tg] * s);
    }
}

__global__ void copy_new_x(const float4* __restrict__ in, float4* __restrict__ out)
{
    int i = blockIdx.x * 256 + threadIdx.x;   // < 49,152
    out[i] = in[i];
}

// R22 structure, launch_bounds(256,4): the last untested cell of the
// bound x structure matrix. R21/R22 showed the compiler settles at ~192
// total unified regs/wave under caps of 256/170 -> 10.6 waves/CU. This
// structure's countable live set is ~116, so the 128-reg cap of (256,4)
// should fit WITHOUT the R8/R18 squeeze (their live sets were 140+) and
// deliver 16 waves/CU = 4 waves/SIMD on a 47%-idle issue port.
__global__ __launch_bounds__(256, 4) void sa_mfma_kernel(
    const float* __restrict__ xg,
    const float* __restrict__ wsf,
    float* __restrict__ feats)
{
    __shared__ __align__(16) ushort W2L[8192];   // 16KB: granule[c 0..7][o 0..127]
    __shared__ __align__(16) ushort W1L[4096];   // 8KB:  granule[c 0..7][o 0..63]
    __shared__ __align__(16) float  B1L[64];     // 256B

    const int tid = threadIdx.x;
    const int w   = tid >> 6;
    const int l   = tid & 63;
    const int r31 = l & 31;
    const int hi5 = l >> 5;

    const ushort* w1b = (const ushort*)((const char*)wsf + W1B);
    const ushort* w2b = (const ushort*)((const char*)wsf + W2B);

    // stage W2' (1024 granules): src gi=(o*8+c) -> dst (c<<7)|o
    {
        const uint4* src = (const uint4*)w2b;
        uint4* dst = (uint4*)W2L;
        for (int gi = tid; gi < 1024; gi += 256)
            dst[((gi & 7) << 7) | (gi >> 3)] = src[gi];
    }
    // stage W1' (512 granules): src gi=(o*8+c) -> dst (c<<6)|o
    {
        const uint4* src = (const uint4*)w1b;
        uint4* dst = (uint4*)W1L;
        for (int gi = tid; gi < 512; gi += 256)
            dst[((gi & 7) << 6) | (gi >> 3)] = src[gi];
    }
    if (tid < 64) B1L[tid] = wsf[B1F + tid];

    const short8 zero8 = {0,0,0,0,0,0,0,0};
    float16v zero16;
#pragma unroll
    for (int i = 0; i < 16; ++i) zero16[i] = 0.f;

    // ---- remaining hoisted weights (small): w0f 8 regs, b2v 4 regs ----
    short8 w0f[2];
#pragma unroll
    for (int ot = 0; ot < 2; ++ot) {
        union { short8 v; unsigned d[4]; } f;
        f.v = zero8;
        if (hi5 == 0) {
            int o = r31 + 32*ot;
            f.d[0] = cvtpk(wsf[W0F + o*3 + 0], wsf[W0F + o*3 + 1]);
            f.d[1] = cvtpk(wsf[W0F + o*3 + 2], wsf[B0F + o]);
        }
        w0f[ot] = f.v;
    }
    float b2v[4];
#pragma unroll
    for (int bt = 0; bt < 4; ++bt)
        b2v[bt] = wsf[B2F + 32*bt + r31];

    __syncthreads();   // W2L/W1L/B1L ready

    const int wid = blockIdx.x * 4 + w;

    // pack+swap: acc layout -> next-layer fragment pair (validated R16)
    auto packswap = [&](const float16v &a, short8 &lo, short8 &hi) {
        unsigned p[8];
#pragma unroll
        for (int q = 0; q < 4; ++q) {
            p[2*q]   = cvtpk(fmaxf(a[4*q+0], 0.f), fmaxf(a[4*q+1], 0.f));
            p[2*q+1] = cvtpk(fmaxf(a[4*q+2], 0.f), fmaxf(a[4*q+3], 0.f));
        }
        union { short8 v; unsigned d[4]; } f0, f1;
        unsigned A = p[0], B = p[2];  plswap(A, B);
        f0.d[0] = A; f0.d[2] = B;
        unsigned C = p[1], D = p[3];  plswap(C, D);
        f0.d[1] = C; f0.d[3] = D;
        unsigned E = p[4], F = p[6];  plswap(E, F);
        f1.d[0] = E; f1.d[2] = F;
        unsigned G = p[5], Hh = p[7]; plswap(G, Hh);
        f1.d[1] = G; f1.d[3] = Hh;
        lo = f0.v; hi = f1.v;
    };

    float xr[3];
    if (hi5 == 0) {
        const float* xp = xg + ((size_t)wid*32 + r31) * 3;
        xr[0] = xp[0]; xr[1] = xp[1]; xr[2] = xp[2];
    }

#pragma unroll 1
    for (int it = 0; it < GITER; ++it) {
        const int g = wid + it * GSTRIDE;

        // x fragment (col = sample r31, k<4 = {x0,x1,x2,1}, hi5==0 half)
        short8 xf;
        {
            union { short8 v; unsigned d[4]; } f;
            f.v = zero8;
            if (hi5 == 0) {
                f.d[0] = cvtpk(xr[0], xr[1]);
                f.d[1] = cvtpk(xr[2], 1.0f);
            }
            xf = f.v;
        }
        if (it + 1 < GITER && hi5 == 0) {
            const float* xp = xg + ((size_t)(g + GSTRIDE)*32 + r31) * 3;
            xr[0] = xp[0]; xr[1] = xp[1]; xr[2] = xp[2];
        }

        // ---- L0: 2 MFMA; pack+swap -> h1f[4] ----
        short8 h1f[4];
#pragma unroll
        for (int ot = 0; ot < 2; ++ot) {
            float16v a = __builtin_amdgcn_mfma_f32_32x32x16_bf16(
                             w0f[ot], xf, zero16, 0, 0, 0);
            packswap(a, h1f[2*ot], h1f[2*ot+1]);
        }

        // ---- L1: 8 MFMA; W1 frags + bias from LDS; pack+swap -> h2f[4] ----
        short8 h2f[4];
#pragma unroll
        for (int ot = 0; ot < 2; ++ot) {
            float16v a;
#pragma unroll
            for (int q = 0; q < 4; ++q) {
                float4v t = *(const float4v*)&B1L[32*ot + 8*q + 4*hi5];
                a[4*q+0] = t[0]; a[4*q+1] = t[1];
                a[4*q+2] = t[2]; a[4*q+3] = t[3];
            }
#pragma unroll
            for (int kt = 0; kt < 4; ++kt) {
                short8 wf = *(const short8*)
                    &W1L[(((2*kt + hi5) << 6) + 32*ot + r31) * 8];
                a = __builtin_amdgcn_mfma_f32_32x32x16_bf16(
                        wf, h1f[kt], a, 0, 0, 0);
            }
            packswap(a, h2f[2*ot], h2f[2*ot+1]);
        }

        // ---- L2: 16 MFMA, W2 frags from W2L; max3-chain epilogue ----
        float* outp = feats + (size_t)g * 128;
#pragma unroll 2
        for (int bt = 0; bt < 4; ++bt) {
            float16v a = zero16;
#pragma unroll
            for (int kt = 0; kt < 4; ++kt) {
                short8 wf = *(const short8*)
                    &W2L[(((2*kt + hi5) << 7) + 32*bt + r31) * 8];
                a = __builtin_amdgcn_mfma_f32_32x32x16_bf16(
                        h2f[kt], wf, a, 0, 0, 0);
            }
            float m = a[0];
#pragma unroll
            for (int i = 1; i < 16; ++i)
                m = fmaxf(m, a[i]);          // clang fuses pairs -> v_max3_f32
            m = fmaxf(m, __shfl_xor(m, 32, 64));
            if (l < 32)
                outp[32*bt + r31] = fmaxf(m + b2v[bt], 0.f);
        }
    }
}

extern "C" void kernel_launch(void* const* d_in, const int* in_sizes, int n_in,
                              void* d_out, int out_size, void* d_ws, size_t ws_size,
                              hipStream_t stream)
{
    const float* xg   = (const float*)d_in[0];
    const float* newx = (const float*)d_in[1];
    const float *W[3], *Bb[3], *G[3], *Be[3], *M[3], *V[3];
    for (int ll = 0; ll < 3; ++ll) {
        W[ll]  = (const float*)d_in[2 + 6*ll + 0];
        Bb[ll] = (const float*)d_in[2 + 6*ll + 1];
        G[ll]  = (const float*)d_in[2 + 6*ll + 2];
        Be[ll] = (const float*)d_in[2 + 6*ll + 3];
        M[ll]  = (const float*)d_in[2 + 6*ll + 4];
        V[ll]  = (const float*)d_in[2 + 6*ll + 5];
    }

    float* wsf = (float*)d_ws;

    fold_kernel<<<32, 256, 0, stream>>>(
        W[0], Bb[0], G[0], Be[0], M[0], V[0],
        W[1], Bb[1], G[1], Be[1], M[1], V[1],
        W[2], Bb[2], G[2], Be[2], M[2], V[2], wsf);

    copy_new_x<<<192, 256, 0, stream>>>((const float4*)newx, (float4*)d_out);

    float* feats = (float*)d_out + NEWX_ELEMS;
    sa_mfma_kernel<<<GRID, 256, 0, stream>>>(xg, wsf, feats);
}

// Round 24
// 69.129 us; speedup vs baseline: 1.0370x; 1.0370x over previous
//
#include <hip/hip_runtime.h>
#include <hip/hip_bf16.h>

#define EPS_BN 1e-5f

typedef __attribute__((ext_vector_type(8)))  short short8;    // 8 x bf16
typedef __attribute__((ext_vector_type(4)))  float float4v;
typedef __attribute__((ext_vector_type(16))) float float16v;  // 32x32 acc

constexpr int NEWX_ELEMS = 196608;    // B*P*3
constexpr int GRID       = 2048;      // 4 waves/block, GITER groups/wave
constexpr int GITER      = 8;
constexpr int GSTRIDE    = GRID * 4;

constexpr int W0F = 0;      // f32[192]  W0' (64x3)
constexpr int B0F = 192;    // f32[64]
constexpr int B1F = 256;    // f32[64]
constexpr int B2F = 320;    // f32[128]
constexpr int W1B = 1792;   // bytes: ushort[4096]  W1' (64x64) bf16
constexpr int W2B = 10240;  // bytes: ushort[8192]  W2' (128x64) bf16

__device__ __forceinline__ unsigned short f2bf(float x) {
    return __builtin_bit_cast(unsigned short, __float2bfloat16(x));
}
__device__ __forceinline__ unsigned cvtpk(float a, float b) {
    unsigned r;
    asm("v_cvt_pk_bf16_f32 %0, %1, %2" : "=v"(r) : "v"(a), "v"(b));
    return r;
}
// gfx950: vdst.high32 <-> vsrc.low32  (HW-validated R16)
__device__ __forceinline__ void plswap(unsigned &a, unsigned &b) {
    asm("v_permlane32_swap_b32 %0, %1" : "+v"(a), "+v"(b));
}

// Merged prologue: fold (blocks 0..31) + new_x copy (blocks 32..223).
// The two tasks are independent; merging removes one launch + tail bubble
// (R23: sa_mfma dispatches at 68.5-69.6us vs 71.0-71.7 end-to-end).
__global__ void prep_kernel(
    const float* w0, const float* b0, const float* g0,
    const float* be0, const float* m0, const float* v0,
    const float* w1, const float* b1, const float* g1,
    const float* be1, const float* m1, const float* v1,
    const float* w2, const float* b2, const float* g2,
    const float* be2, const float* m2, const float* v2,
    const float4* __restrict__ newx, float4* __restrict__ newx_out,
    float* __restrict__ ws)
{
    if (blockIdx.x >= 32) {
        int i = (blockIdx.x - 32) * 256 + threadIdx.x;   // < 49,152
        newx_out[i] = newx[i];
        return;
    }
    const int tg = blockIdx.x * 256 + threadIdx.x;   // 0..8191
    ushort* w1b = (ushort*)((char*)ws + W1B);
    ushort* w2b = (ushort*)((char*)ws + W2B);
    if (tg < 64) {
        float s0 = g0[tg] * rsqrtf(v0[tg] + EPS_BN);
        ws[B0F + tg] = (b0[tg] - m0[tg]) * s0 + be0[tg];
        ws[W0F + tg*3 + 0] = w0[tg*3 + 0] * s0;
        ws[W0F + tg*3 + 1] = w0[tg*3 + 1] * s0;
        ws[W0F + tg*3 + 2] = w0[tg*3 + 2] * s0;
        float s1 = g1[tg] * rsqrtf(v1[tg] + EPS_BN);
        ws[B1F + tg] = (b1[tg] - m1[tg]) * s1 + be1[tg];
    }
    if (tg < 128) {
        float s2 = g2[tg] * rsqrtf(v2[tg] + EPS_BN);
        ws[B2F + tg] = (b2[tg] - m2[tg]) * s2 + be2[tg];
    }
    if (tg < 4096) {
        int o = tg >> 6;
        float s = g1[o] * rsqrtf(v1[o] + EPS_BN);
        w1b[tg] = f2bf(w1[tg] * s);
    }
    if (tg < 8192) {
        int o = tg >> 6;
        float s = g2[o] * rsqrtf(v2[o] + EPS_BN);
        w2b[tg] = f2bf(w2[tg] * s);
    }
}

// R22 champion structure, unchanged: all-register layer chain (32x32x16
// MFMA; permlane redistribution), W1/B1/W2 in LDS, GITER=8, max3 epilogue,
// launch_bounds(256,3). R20-R23 established the allocator settles at ~192
// total unified regs/wave under any non-squeezing bound -> ~2.6 waves/SIMD;
// the remaining ~45% idle is dependency-stall at that structural cap.
__global__ __launch_bounds__(256, 3) void sa_mfma_kernel(
    const float* __restrict__ xg,
    const float* __restrict__ wsf,
    float* __restrict__ feats)
{
    __shared__ __align__(16) ushort W2L[8192];   // 16KB: granule[c 0..7][o 0..127]
    __shared__ __align__(16) ushort W1L[4096];   // 8KB:  granule[c 0..7][o 0..63]
    __shared__ __align__(16) float  B1L[64];     // 256B

    const int tid = threadIdx.x;
    const int w   = tid >> 6;
    const int l   = tid & 63;
    const int r31 = l & 31;
    const int hi5 = l >> 5;

    const ushort* w1b = (const ushort*)((const char*)wsf + W1B);
    const ushort* w2b = (const ushort*)((const char*)wsf + W2B);

    // stage W2' (1024 granules): src gi=(o*8+c) -> dst (c<<7)|o
    {
        const uint4* src = (const uint4*)w2b;
        uint4* dst = (uint4*)W2L;
        for (int gi = tid; gi < 1024; gi += 256)
            dst[((gi & 7) << 7) | (gi >> 3)] = src[gi];
    }
    // stage W1' (512 granules): src gi=(o*8+c) -> dst (c<<6)|o
    {
        const uint4* src = (const uint4*)w1b;
        uint4* dst = (uint4*)W1L;
        for (int gi = tid; gi < 512; gi += 256)
            dst[((gi & 7) << 6) | (gi >> 3)] = src[gi];
    }
    if (tid < 64) B1L[tid] = wsf[B1F + tid];

    const short8 zero8 = {0,0,0,0,0,0,0,0};
    float16v zero16;
#pragma unroll
    for (int i = 0; i < 16; ++i) zero16[i] = 0.f;

    // ---- remaining hoisted weights (small): w0f 8 regs, b2v 4 regs ----
    short8 w0f[2];
#pragma unroll
    for (int ot = 0; ot < 2; ++ot) {
        union { short8 v; unsigned d[4]; } f;
        f.v = zero8;
        if (hi5 == 0) {
            int o = r31 + 32*ot;
            f.d[0] = cvtpk(wsf[W0F + o*3 + 0], wsf[W0F + o*3 + 1]);
            f.d[1] = cvtpk(wsf[W0F + o*3 + 2], wsf[B0F + o]);
        }
        w0f[ot] = f.v;
    }
    float b2v[4];
#pragma unroll
    for (int bt = 0; bt < 4; ++bt)
        b2v[bt] = wsf[B2F + 32*bt + r31];

    __syncthreads();   // W2L/W1L/B1L ready

    const int wid = blockIdx.x * 4 + w;

    // pack+swap: acc layout -> next-layer fragment pair (validated R16)
    auto packswap = [&](const float16v &a, short8 &lo, short8 &hi) {
        unsigned p[8];
#pragma unroll
        for (int q = 0; q < 4; ++q) {
            p[2*q]   = cvtpk(fmaxf(a[4*q+0], 0.f), fmaxf(a[4*q+1], 0.f));
            p[2*q+1] = cvtpk(fmaxf(a[4*q+2], 0.f), fmaxf(a[4*q+3], 0.f));
        }
        union { short8 v; unsigned d[4]; } f0, f1;
        unsigned A = p[0], B = p[2];  plswap(A, B);
        f0.d[0] = A; f0.d[2] = B;
        unsigned C = p[1], D = p[3];  plswap(C, D);
        f0.d[1] = C; f0.d[3] = D;
        unsigned E = p[4], F = p[6];  plswap(E, F);
        f1.d[0] = E; f1.d[2] = F;
        unsigned G = p[5], Hh = p[7]; plswap(G, Hh);
        f1.d[1] = G; f1.d[3] = Hh;
        lo = f0.v; hi = f1.v;
    };

    float xr[3];
    if (hi5 == 0) {
        const float* xp = xg + ((size_t)wid*32 + r31) * 3;
        xr[0] = xp[0]; xr[1] = xp[1]; xr[2] = xp[2];
    }

#pragma unroll 1
    for (int it = 0; it < GITER; ++it) {
        const int g = wid + it * GSTRIDE;

        // x fragment (col = sample r31, k<4 = {x0,x1,x2,1}, hi5==0 half)
        short8 xf;
        {
            union { short8 v; unsigned d[4]; } f;
            f.v = zero8;
            if (hi5 == 0) {
                f.d[0] = cvtpk(xr[0], xr[1]);
                f.d[1] = cvtpk(xr[2], 1.0f);
            }
            xf = f.v;
        }
        if (it + 1 < GITER && hi5 == 0) {
            const float* xp = xg + ((size_t)(g + GSTRIDE)*32 + r31) * 3;
            xr[0] = xp[0]; xr[1] = xp[1]; xr[2] = xp[2];
        }

        // ---- L0: 2 MFMA; pack+swap -> h1f[4] ----
        short8 h1f[4];
#pragma unroll
        for (int ot = 0; ot < 2; ++ot) {
            float16v a = __builtin_amdgcn_mfma_f32_32x32x16_bf16(
                             w0f[ot], xf, zero16, 0, 0, 0);
            packswap(a, h1f[2*ot], h1f[2*ot+1]);
        }

        // ---- L1: 8 MFMA; W1 frags + bias from LDS; pack+swap -> h2f[4] ----
        short8 h2f[4];
#pragma unroll
        for (int ot = 0; ot < 2; ++ot) {
            float16v a;
#pragma unroll
            for (int q = 0; q < 4; ++q) {
                float4v t = *(const float4v*)&B1L[32*ot + 8*q + 4*hi5];
                a[4*q+0] = t[0]; a[4*q+1] = t[1];
                a[4*q+2] = t[2]; a[4*q+3] = t[3];
            }
#pragma unroll
            for (int kt = 0; kt < 4; ++kt) {
                short8 wf = *(const short8*)
                    &W1L[(((2*kt + hi5) << 6) + 32*ot + r31) * 8];
                a = __builtin_amdgcn_mfma_f32_32x32x16_bf16(
                        wf, h1f[kt], a, 0, 0, 0);
            }
            packswap(a, h2f[2*ot], h2f[2*ot+1]);
        }

        // ---- L2: 16 MFMA, W2 frags from W2L; max3-chain epilogue ----
        float* outp = feats + (size_t)g * 128;
#pragma unroll 2
        for (int bt = 0; bt < 4; ++bt) {
            float16v a = zero16;
#pragma unroll
            for (int kt = 0; kt < 4; ++kt) {
                short8 wf = *(const short8*)
                    &W2L[(((2*kt + hi5) << 7) + 32*bt + r31) * 8];
                a = __builtin_amdgcn_mfma_f32_32x32x16_bf16(
                        h2f[kt], wf, a, 0, 0, 0);
            }
            float m = a[0];
#pragma unroll
            for (int i = 1; i < 16; ++i)
                m = fmaxf(m, a[i]);          // clang fuses pairs -> v_max3_f32
            m = fmaxf(m, __shfl_xor(m, 32, 64));
            if (l < 32)
                outp[32*bt + r31] = fmaxf(m + b2v[bt], 0.f);
        }
    }
}

extern "C" void kernel_launch(void* const* d_in, const int* in_sizes, int n_in,
                              void* d_out, int out_size, void* d_ws, size_t ws_size,
                              hipStream_t stream)
{
    const float* xg   = (const float*)d_in[0];
    const float* newx = (const float*)d_in[1];
    const float *W[3], *Bb[3], *G[3], *Be[3], *M[3], *V[3];
    for (int ll = 0; ll < 3; ++ll) {
        W[ll]  = (const float*)d_in[2 + 6*ll + 0];
        Bb[ll] = (const float*)d_in[2 + 6*ll + 1];
        G[ll]  = (const float*)d_in[2 + 6*ll + 2];
        Be[ll] = (const float*)d_in[2 + 6*ll + 3];
        M[ll]  = (const float*)d_in[2 + 6*ll + 4];
        V[ll]  = (const float*)d_in[2 + 6*ll + 5];
    }

    float* wsf = (float*)d_ws;

    prep_kernel<<<224, 256, 0, stream>>>(
        W[0], Bb[0], G[0], Be[0], M[0], V[0],
        W[1], Bb[1], G[1], Be[1], M[1], V[1],
        W[2], Bb[2], G[2], Be[2], M[2], V[2],
        (const float4*)newx, (float4*)d_out, wsf);

    float* feats = (float*)d_out + NEWX_ELEMS;
    sa_mfma_kernel<<<GRID, 256, 0, stream>>>(xg, wsf, feats);
}